// Round 5
// baseline (258.539 us; speedup 1.0000x reference)
//
#include <hip/hip_runtime.h>
#include <hip/hip_bf16.h>
#include <math.h>

typedef _Float16 f16;
typedef _Float16 f16x4 __attribute__((ext_vector_type(4)));
typedef _Float16 f16x8 __attribute__((ext_vector_type(8)));
typedef float f32x4 __attribute__((ext_vector_type(4)));

#define HD 64
#define NH 16
#define BATCH 2
#define SEQ 2048
#define DMODEL 1024
#define NQKV 3072
#define ROWS 4096
#define NEG_BIG (-1.0e30f)
// 0.125 * log2(e): softmax done in base-2 domain (v_exp_f32 is 2^x native)
#define SCALE_LOG2E 0.18033688011112042f

__device__ __forceinline__ f32x4 mfma16h(f16x8 a, f16x8 b, f32x4 c){
  return __builtin_amdgcn_mfma_f32_16x16x32_f16(a, b, c, 0, 0, 0);
}

// global -> LDS async copy, 16B per lane, dest = wave-uniform base + lane*16
__device__ __forceinline__ void gload16(const f16* g, f16* l){
  __builtin_amdgcn_global_load_lds(
      (const __attribute__((address_space(1))) unsigned int*)(g),
      (__attribute__((address_space(3))) unsigned int*)(l), 16, 0, 0);
}

// ---------------- LayerNorm: fp32 in, f16 out (float4 vectorized) ----------
__global__ __launch_bounds__(256) void ln_kernel(const float* __restrict__ x,
    const float* __restrict__ gamma, const float* __restrict__ beta,
    f16* __restrict__ xn)
{
  int row = blockIdx.x;
  int tid = threadIdx.x;
  float4 v = ((const float4*)(x + (size_t)row * DMODEL))[tid];
  float s  = v.x + v.y + v.z + v.w;
  float s2 = v.x*v.x + v.y*v.y + v.z*v.z + v.w*v.w;
  #pragma unroll
  for (int off = 32; off; off >>= 1){ s += __shfl_xor(s, off); s2 += __shfl_xor(s2, off); }
  __shared__ float red[8];
  int wave = tid >> 6, lane = tid & 63;
  if (lane == 0){ red[wave] = s; red[4 + wave] = s2; }
  __syncthreads();
  s  = red[0] + red[1] + red[2] + red[3];
  s2 = red[4] + red[5] + red[6] + red[7];
  float mu  = s * (1.f / DMODEL);
  float var = s2 * (1.f / DMODEL) - mu * mu;
  float rs  = rsqrtf(var + 1e-5f);
  float4 g  = ((const float4*)gamma)[tid];
  float4 be = ((const float4*)beta)[tid];
  f16x4 o;
  o[0] = (f16)((v.x - mu) * rs * g.x + be.x);
  o[1] = (f16)((v.y - mu) * rs * g.y + be.y);
  o[2] = (f16)((v.z - mu) * rs * g.z + be.z);
  o[3] = (f16)((v.w - mu) * rs * g.w + be.w);
  *(f16x4*)(xn + (size_t)row * DMODEL + tid*4) = o;
}

// ------------- Transpose fp32 RxC -> f16 CxR -------------
__global__ __launch_bounds__(256) void transpose_f2h_kernel(const float* __restrict__ in,
    f16* __restrict__ out, int R, int C)
{
  __shared__ float t[32][33];
  int c0 = blockIdx.x * 32, r0 = blockIdx.y * 32;
  int lx = threadIdx.x & 31, ly = threadIdx.x >> 5;
  #pragma unroll
  for (int i = 0; i < 32; i += 8) t[ly + i][lx] = in[(size_t)(r0 + ly + i) * C + c0 + lx];
  __syncthreads();
  #pragma unroll
  for (int i = 0; i < 32; i += 8) out[(size_t)(c0 + ly + i) * R + r0 + lx] = (f16)t[lx][ly + i];
}

// ---------------- QKV GEMM: A[4096,1024]f16 x Bt[3072,1024]f16 -> scatter QKV
__global__ __launch_bounds__(256, 3) void gemm_qkv(const f16* __restrict__ A,
    const f16* __restrict__ Bt, f16* __restrict__ Qo, f16* __restrict__ Ko,
    f16* __restrict__ Vo)
{
  __shared__ __align__(16) f16 As[2][128][32];
  __shared__ __align__(16) f16 Bs[2][128][32];
  const int K = DMODEL;
  int bm = blockIdx.y * 128, bn = blockIdx.x * 128;
  int tid = threadIdx.x;
  int wave = tid >> 6, lane = tid & 63, quad = lane >> 4, l15 = lane & 15;
  int mw = (wave >> 1) * 64, nw = (wave & 1) * 64;

  int sr0 = wave*16 + (lane >> 2);          // rows 0..63
  int sr1 = sr0 + 64;                       // rows 64..127 (same &3)
  int sc  = (lane & 3) ^ (sr0 & 3);         // inverse-swizzled source chunk
  const f16* Ag = A  + (size_t)bm * K;
  const f16* Bg = Bt + (size_t)bn * K;
  f16* ldsA0 = &As[0][wave*16     ][0];
  f16* ldsA1 = &As[0][wave*16 + 64][0];
  f16* ldsB0 = &Bs[0][wave*16     ][0];
  f16* ldsB1 = &Bs[0][wave*16 + 64][0];

#define QSTAGE(buf, k0) do{ \
    gload16(Ag + (size_t)sr0 * K + (k0) + sc*8, ldsA0 + (buf)*4096); \
    gload16(Ag + (size_t)sr1 * K + (k0) + sc*8, ldsA1 + (buf)*4096); \
    gload16(Bg + (size_t)sr0 * K + (k0) + sc*8, ldsB0 + (buf)*4096); \
    gload16(Bg + (size_t)sr1 * K + (k0) + sc*8, ldsB1 + (buf)*4096); }while(0)

  f32x4 zero = {0.f, 0.f, 0.f, 0.f};
  f32x4 acc[4][4];
  #pragma unroll
  for (int i = 0; i < 4; i++)
    #pragma unroll
    for (int j = 0; j < 4; j++) acc[i][j] = zero;

  QSTAGE(0, 0);
  const int NS = K / 32;
  for (int it = 0; it < NS; ++it){
    int cur = it & 1;
    asm volatile("s_waitcnt vmcnt(0)" ::: "memory");
    __syncthreads();
    if (it + 1 < NS) QSTAGE(cur ^ 1, (it + 1) * 32);
    int ca = (quad ^ (l15 & 3)) * 8;
    f16x8 af[4], bfr[4];
    #pragma unroll
    for (int i = 0; i < 4; i++) af[i]  = *(const f16x8*)&As[cur][mw + i*16 + l15][ca];
    #pragma unroll
    for (int i = 0; i < 4; i++) bfr[i] = *(const f16x8*)&Bs[cur][nw + i*16 + l15][ca];
    __builtin_amdgcn_s_setprio(1);
    #pragma unroll
    for (int mi = 0; mi < 4; mi++)
      #pragma unroll
      for (int ni = 0; ni < 4; ni++)
        acc[mi][ni] = mfma16h(af[mi], bfr[ni], acc[mi][ni]);
    __builtin_amdgcn_s_setprio(0);
  }
#undef QSTAGE

  #pragma unroll
  for (int mi = 0; mi < 4; mi++){
    #pragma unroll
    for (int ni = 0; ni < 4; ni++){
      int c = bn + nw + ni*16 + l15;
      int which = c >> 10;
      int hc = c & 1023;
      int h = hc >> 6, d = hc & 63;
      if (which == 2){
        // V: 4 regs are 4 consecutive nseq at fixed d -> one f16x4 store
        int r = bm + mw + mi*16 + quad*4;
        int b = r >> 11, nseq = r & 2047;
        size_t bh = (size_t)(b * NH + h);
        f16x4 vv;
        #pragma unroll
        for (int reg = 0; reg < 4; reg++) vv[reg] = (f16)acc[mi][ni][reg];
        *(f16x4*)(Vo + (bh * HD + d) * SEQ + nseq) = vv;
      } else {
        #pragma unroll
        for (int reg = 0; reg < 4; reg++){
          int r = bm + mw + mi*16 + quad*4 + reg;
          float v = acc[mi][ni][reg];
          int b = r >> 11, nseq = r & 2047;
          size_t bh = (size_t)(b * NH + h);
          if (which == 0) Qo[(bh * SEQ + nseq) * HD + d] = (f16)v;
          else            Ko[(bh * SEQ + nseq) * HD + d] = (f16)v;
        }
      }
    }
  }
}

// ---------------- Out GEMM: BM=64, BN=128 -> 512 blocks, fp32 store --------
__global__ __launch_bounds__(256, 4) void gemm_out(const f16* __restrict__ A,
    const f16* __restrict__ Bt, float* __restrict__ C, int M, int N, int K)
{
  __shared__ __align__(16) f16 As[2][64][32];
  __shared__ __align__(16) f16 Bs[2][128][32];
  int bm = blockIdx.y * 64, bn = blockIdx.x * 128;
  int tid = threadIdx.x;
  int wave = tid >> 6, lane = tid & 63, quad = lane >> 4, l15 = lane & 15;
  int mw = (wave >> 1) * 32, nw = (wave & 1) * 64;

  int sr0 = wave*16 + (lane >> 2);          // 0..63
  int sc  = (lane & 3) ^ (sr0 & 3);
  const f16* Ag = A  + (size_t)bm * K;
  const f16* Bg = Bt + (size_t)bn * K;
  f16* ldsA0 = &As[0][wave*16     ][0];
  f16* ldsB0 = &Bs[0][wave*16     ][0];
  f16* ldsB1 = &Bs[0][wave*16 + 64][0];

#define OSTAGE(buf, k0) do{ \
    gload16(Ag + (size_t)sr0 * K + (k0) + sc*8, ldsA0 + (buf)*2048); \
    gload16(Bg + (size_t)sr0 * K + (k0) + sc*8, ldsB0 + (buf)*4096); \
    gload16(Bg + (size_t)(sr0 + 64) * K + (k0) + sc*8, ldsB1 + (buf)*4096); }while(0)

  f32x4 zero = {0.f, 0.f, 0.f, 0.f};
  f32x4 acc[2][4];
  #pragma unroll
  for (int i = 0; i < 2; i++)
    #pragma unroll
    for (int j = 0; j < 4; j++) acc[i][j] = zero;

  OSTAGE(0, 0);
  const int NS = DMODEL / 32;
  for (int it = 0; it < NS; ++it){
    int cur = it & 1;
    asm volatile("s_waitcnt vmcnt(0)" ::: "memory");
    __syncthreads();
    if (it + 1 < NS) OSTAGE(cur ^ 1, (it + 1) * 32);
    int ca = (quad ^ (l15 & 3)) * 8;
    f16x8 af[2], bfr[4];
    #pragma unroll
    for (int i = 0; i < 2; i++) af[i]  = *(const f16x8*)&As[cur][mw + i*16 + l15][ca];
    #pragma unroll
    for (int i = 0; i < 4; i++) bfr[i] = *(const f16x8*)&Bs[cur][nw + i*16 + l15][ca];
    __builtin_amdgcn_s_setprio(1);
    #pragma unroll
    for (int mi = 0; mi < 2; mi++)
      #pragma unroll
      for (int ni = 0; ni < 4; ni++)
        acc[mi][ni] = mfma16h(af[mi], bfr[ni], acc[mi][ni]);
    __builtin_amdgcn_s_setprio(0);
  }
#undef OSTAGE

  #pragma unroll
  for (int mi = 0; mi < 2; mi++)
    #pragma unroll
    for (int ni = 0; ni < 4; ni++)
      #pragma unroll
      for (int reg = 0; reg < 4; reg++){
        int r = bm + mw + mi*16 + quad*4 + reg;
        int c = bn + nw + ni*16 + l15;
        C[(size_t)r * N + c] = acc[mi][ni][reg];
      }
}

// ---------------- Flash attention: dots = (QK^T + m) * SCALE ----
// QBLK=128: each wave owns TWO q-subtiles (u=0,1; 32 q-rows). K/V fragments
// read from LDS ONCE feed two MFMAs (amortization). Swapped QK^T keeps the
// softmax row lane-local. Defer-max (THR=8, base-2 domain). K/V double-
// buffered gload_lds tiles with XOR swizzle, one barrier per j-tile.
// LDS = 16K(K)+16K(V)+16K(Ps) = 49152 -> grid 512 = 2 blocks/CU.
__global__ __launch_bounds__(256, 2) void attn_kernel(const f16* __restrict__ Q,
    const f16* __restrict__ Kb, const f16* __restrict__ Vt,
    const float* __restrict__ mask, f16* __restrict__ Ao)
{
  __shared__ __align__(16) f16 KsB[2][64*64];
  __shared__ __align__(16) f16 VsB[2][64*64];
  __shared__ __align__(16) f16 Ps[8*16*64];   // 4 waves x 2 u x 16 x 64

  int bh = blockIdx.y; int b = bh >> 4; int h = bh & 15;
  int q0 = blockIdx.x * 128;
  int tid = threadIdx.x;
  int wave = tid >> 6, lane = tid & 63, quad = lane >> 4, l15 = lane & 15;

  // staging geometry: per wave 2 K-insts + 2 V-insts, each 8 rows x 128B
  int rA = (wave*2 + 0)*8 + (lane >> 3);
  int rB = (wave*2 + 1)*8 + (lane >> 3);
  int cp = lane & 7;
  int ccA = cp ^ (rA & 7);
  int ccB = cp ^ (rB & 7);
  const f16* Kg = Kb + (size_t)bh * SEQ * HD;
  const f16* Vg = Vt + (size_t)bh * HD * SEQ;
  f16* ldsKA = &KsB[0][0] + (wave*2 + 0)*8*64;
  f16* ldsKB = &KsB[0][0] + (wave*2 + 1)*8*64;
  f16* ldsVA = &VsB[0][0] + (wave*2 + 0)*8*64;
  f16* ldsVB = &VsB[0][0] + (wave*2 + 1)*8*64;

  // Q fragments: loop-invariant, straight from global (2 q-subtiles per wave)
  f16x8 qf[2][2];
  #pragma unroll
  for (int u = 0; u < 2; u++){
    const f16* qrow = Q + ((size_t)bh * SEQ + q0 + wave*32 + u*16 + l15) * HD + quad*8;
    qf[u][0] = *(const f16x8*)(qrow);
    qf[u][1] = *(const f16x8*)(qrow + 32);
  }

  // per-thread mask rows (i = q0 + wave*32 + u*16 + l15), col offset quad*4
  const float* mrow[2];
  #pragma unroll
  for (int u = 0; u < 2; u++)
    mrow[u] = mask + ((size_t)b * SEQ + q0 + wave*32 + u*16 + l15) * SEQ + quad*4;

  // prologue: stage tile 0 into buffer 0
  gload16(Kg + (size_t)(0 + rA)*HD + ccA*8, ldsKA);
  gload16(Kg + (size_t)(0 + rB)*HD + ccB*8, ldsKB);
  gload16(Vg + (size_t)rA*SEQ + 0 + ccA*8, ldsVA);
  gload16(Vg + (size_t)rB*SEQ + 0 + ccB*8, ldsVB);

  f32x4 zero = {0.f, 0.f, 0.f, 0.f};
  f32x4 O[2][4];
  #pragma unroll
  for (int u = 0; u < 2; u++)
    #pragma unroll
    for (int nt = 0; nt < 4; nt++) O[u][nt] = zero;
  float mrun[2] = {NEG_BIG, NEG_BIG}, lrun[2] = {0.f, 0.f};

  const int NT = SEQ / 64;
  for (int it = 0; it < NT; ++it){
    int cur = it & 1;
    int j0 = it * 64;
    asm volatile("s_waitcnt vmcnt(0)" ::: "memory");
    __syncthreads();
    if (it + 1 < NT){
      int nb = cur ^ 1;
      int j0n = j0 + 64;
      gload16(Kg + (size_t)(j0n + rA)*HD + ccA*8, ldsKA + nb*4096);
      gload16(Kg + (size_t)(j0n + rB)*HD + ccB*8, ldsKB + nb*4096);
      gload16(Vg + (size_t)rA*SEQ + j0n + ccA*8, ldsVA + nb*4096);
      gload16(Vg + (size_t)rB*SEQ + j0n + ccB*8, ldsVB + nb*4096);
    }
    const f16* Ksc = &KsB[cur][0];
    const f16* Vsc = &VsB[cur][0];

    // mask loads issued early: latency overlaps the QK MFMA section
    float4 mc[2][4];
    #pragma unroll
    for (int u = 0; u < 2; u++)
      #pragma unroll
      for (int jt = 0; jt < 4; jt++)
        mc[u][jt] = *(const float4*)(mrow[u] + j0 + jt*16);

    // ---- QK^T (swapped) + mask: kf read once feeds both u ----
    float sv[2][4][4];   // [u][jt][reg]: S[i=l15][j = j0 + jt*16 + quad*4 + reg]
    __builtin_amdgcn_s_setprio(1);
    #pragma unroll
    for (int jt = 0; jt < 4; jt++){
      int r = jt*16 + l15;
      f16x8 kf0 = *(const f16x8*)&Ksc[r*64 + (((0 + quad) ^ (r & 7))*8)];
      f16x8 kf1 = *(const f16x8*)&Ksc[r*64 + (((4 + quad) ^ (r & 7))*8)];
      #pragma unroll
      for (int u = 0; u < 2; u++){
        f32x4 a = zero;
        a = mfma16h(kf0, qf[u][0], a);
        a = mfma16h(kf1, qf[u][1], a);
        sv[u][jt][0] = (a[0] + mc[u][jt].x) * SCALE_LOG2E;
        sv[u][jt][1] = (a[1] + mc[u][jt].y) * SCALE_LOG2E;
        sv[u][jt][2] = (a[2] + mc[u][jt].z) * SCALE_LOG2E;
        sv[u][jt][3] = (a[3] + mc[u][jt].w) * SCALE_LOG2E;
      }
    }
    __builtin_amdgcn_s_setprio(0);

    // ---- softmax per u (row lane-local; defer-max) ----
    #pragma unroll
    for (int u = 0; u < 2; u++){
      float m0 = fmaxf(fmaxf(sv[u][0][0], sv[u][0][1]), fmaxf(sv[u][0][2], sv[u][0][3]));
      float m1 = fmaxf(fmaxf(sv[u][1][0], sv[u][1][1]), fmaxf(sv[u][1][2], sv[u][1][3]));
      float m2 = fmaxf(fmaxf(sv[u][2][0], sv[u][2][1]), fmaxf(sv[u][2][2], sv[u][2][3]));
      float m3 = fmaxf(fmaxf(sv[u][3][0], sv[u][3][1]), fmaxf(sv[u][3][2], sv[u][3][3]));
      float tmax = fmaxf(fmaxf(m0, m1), fmaxf(m2, m3));
      tmax = fmaxf(tmax, __shfl_xor(tmax, 16));
      tmax = fmaxf(tmax, __shfl_xor(tmax, 32));

      if (__any(tmax > mrun[u] + 8.f)){
        float nm = fmaxf(mrun[u], tmax);
        float alpha = exp2f(mrun[u] - nm);
        mrun[u] = nm;
        lrun[u] *= alpha;
        float aR[4];
        #pragma unroll
        for (int reg = 0; reg < 4; reg++)
          aR[reg] = __shfl(alpha, (lane & 48) | (quad*4 + reg));
        #pragma unroll
        for (int nt = 0; nt < 4; nt++)
          #pragma unroll
          for (int reg = 0; reg < 4; reg++) O[u][nt][reg] *= aR[reg];
      }

      float ps = 0.f;
      #pragma unroll
      for (int jt = 0; jt < 4; jt++)
        #pragma unroll
        for (int reg = 0; reg < 4; reg++){
          float p = exp2f(sv[u][jt][reg] - mrun[u]);
          sv[u][jt][reg] = p; ps += p;
        }
      lrun[u] += ps;   // per-quad partial; cross-quad combine deferred to epilogue

      // ---- P -> LDS (same-wave slab, swizzled: no barrier) ----
      #pragma unroll
      for (int jt = 0; jt < 4; jt++){
        f16x4 ph;
        ph[0] = (f16)sv[u][jt][0]; ph[1] = (f16)sv[u][jt][1];
        ph[2] = (f16)sv[u][jt][2]; ph[3] = (f16)sv[u][jt][3];
        *(f16x4*)&Ps[wave*2048 + u*1024 + l15*64
                     + (((jt*2 + (quad>>1)) ^ (l15 & 7))*8) + (quad & 1)*4] = ph;
      }
    }

    // ---- PV: vf read once feeds both u ----
    f16x8 pf[2][2];
    #pragma unroll
    for (int u = 0; u < 2; u++)
      #pragma unroll
      for (int kk = 0; kk < 2; kk++)
        pf[u][kk] = *(const f16x8*)&Ps[wave*2048 + u*1024 + l15*64
                                       + (((kk*4 + quad) ^ (l15 & 7))*8)];
    __builtin_amdgcn_s_setprio(1);
    #pragma unroll
    for (int nt = 0; nt < 4; nt++){
      int rv = nt*16 + l15;
      f16x8 vf0 = *(const f16x8*)&Vsc[rv*64 + (((0 + quad) ^ (rv & 7))*8)];
      f16x8 vf1 = *(const f16x8*)&Vsc[rv*64 + (((4 + quad) ^ (rv & 7))*8)];
      #pragma unroll
      for (int u = 0; u < 2; u++){
        O[u][nt] = mfma16h(pf[u][0], vf0, O[u][nt]);
        O[u][nt] = mfma16h(pf[u][1], vf1, O[u][nt]);
      }
    }
    __builtin_amdgcn_s_setprio(0);
  }

  // ---- epilogue: combine per-quad partial sums, redistribute, store ----
  #pragma unroll
  for (int u = 0; u < 2; u++){
    float l = lrun[u];
    l += __shfl_xor(l, 16);
    l += __shfl_xor(l, 32);
    float lR[4];
    #pragma unroll
    for (int reg = 0; reg < 4; reg++)
      lR[reg] = __shfl(l, (lane & 48) | (quad*4 + reg));
    #pragma unroll
    for (int nt = 0; nt < 4; nt++){
      #pragma unroll
      for (int reg = 0; reg < 4; reg++){
        float o = O[u][nt][reg] / lR[reg];
        int r = q0 + wave*32 + u*16 + quad*4 + reg;
        Ao[((size_t)(b * SEQ + r)) * DMODEL + h * HD + nt*16 + l15] = (f16)o;
      }
    }
  }
}

// ---------------- launch ----------------
// OUTPUT IS FP32. ws (>=48 MiB verified by probe):
//   xn f16 @0 (Ao alias after QKV) | Qb @8M (WoutT alias after attn)
//   Kb @16M | Vt @24M | WqkvT @32M (6MB)
extern "C" void kernel_launch(void* const* d_in, const int* in_sizes, int n_in,
                              void* d_out, int out_size, void* d_ws, size_t ws_size,
                              hipStream_t stream)
{
  (void)in_sizes; (void)n_in; (void)out_size; (void)ws_size;
  const float* x     = (const float*)d_in[0];
  const float* m     = (const float*)d_in[1];
  const float* gamma = (const float*)d_in[2];
  const float* beta  = (const float*)d_in[3];
  const float* Wqkv  = (const float*)d_in[4];
  const float* Wout  = (const float*)d_in[5];
  float* out = (float*)d_out;

  char* ws = (char*)d_ws;
  f16* xn    = (f16*)(ws + 0);
  f16* Ao    = (f16*)(ws + 0);            // alias: xn dead after gemm_qkv
  f16* Qb    = (f16*)(ws + 8388608);
  f16* WoutT = (f16*)(ws + 8388608);      // alias: Qb dead after attn
  f16* Kbuf  = (f16*)(ws + 16777216);
  f16* Vtb   = (f16*)(ws + 25165824);
  f16* WqkvT = (f16*)(ws + 33554432);

  ln_kernel<<<ROWS, 256, 0, stream>>>(x, gamma, beta, xn);
  transpose_f2h_kernel<<<dim3(NQKV/32, DMODEL/32), 256, 0, stream>>>(Wqkv, WqkvT, DMODEL, NQKV);
  gemm_qkv<<<dim3(NQKV/128, ROWS/128), 256, 0, stream>>>(xn, WqkvT, Qb, Kbuf, Vtb);
  attn_kernel<<<dim3(SEQ/128, BATCH*NH), 256, 0, stream>>>(Qb, Kbuf, Vtb, m, Ao);
  transpose_f2h_kernel<<<dim3(DMODEL/32, DMODEL/32), 256, 0, stream>>>(Wout, WoutT, DMODEL, DMODEL);
  gemm_out<<<dim3(DMODEL/128, ROWS/64), 256, 0, stream>>>(Ao, WoutT, out, ROWS, DMODEL, DMODEL);
}

// Round 7
// 256.676 us; speedup vs baseline: 1.0073x; 1.0073x over previous
//
#include <hip/hip_runtime.h>
#include <hip/hip_bf16.h>
#include <math.h>

typedef _Float16 f16;
typedef __fp16 hf2 __attribute__((ext_vector_type(2)));
typedef _Float16 f16x4 __attribute__((ext_vector_type(4)));
typedef _Float16 f16x8 __attribute__((ext_vector_type(8)));
typedef float f32x4 __attribute__((ext_vector_type(4)));
typedef float f32x16 __attribute__((ext_vector_type(16)));
typedef unsigned int u32x2 __attribute__((ext_vector_type(2)));

#define HD 64
#define NH 16
#define BATCH 2
#define SEQ 2048
#define DMODEL 1024
#define NQKV 3072
#define ROWS 4096
#define NEG_BIG (-1.0e30f)
// 0.125 * log2(e): softmax in base-2 domain; folded into Q at gemm_qkv epilogue
#define SCALE_LOG2E 0.18033688011112042f

__device__ __forceinline__ f32x4 mfma16h(f16x8 a, f16x8 b, f32x4 c){
  return __builtin_amdgcn_mfma_f32_16x16x32_f16(a, b, c, 0, 0, 0);
}
__device__ __forceinline__ f32x16 mfma32h(f16x8 a, f16x8 b, f32x16 c){
  return __builtin_amdgcn_mfma_f32_32x32x16_f16(a, b, c, 0, 0, 0);
}
__device__ __forceinline__ u32x2 pswap(unsigned a, unsigned b){
  return __builtin_amdgcn_permlane32_swap(a, b, false, false);
}
__device__ __forceinline__ unsigned pk16(float a, float b){
  hf2 r = __builtin_amdgcn_cvt_pkrtz(a, b);
  return __builtin_bit_cast(unsigned, r);
}

// global -> LDS async copy, 16B per lane, dest = wave-uniform base + lane*16
__device__ __forceinline__ void gload16(const f16* g, f16* l){
  __builtin_amdgcn_global_load_lds(
      (const __attribute__((address_space(1))) unsigned int*)(g),
      (__attribute__((address_space(3))) unsigned int*)(l), 16, 0, 0);
}

// ---------------- LayerNorm: fp32 in, f16 out (float4 vectorized) ----------
__global__ __launch_bounds__(256) void ln_kernel(const float* __restrict__ x,
    const float* __restrict__ gamma, const float* __restrict__ beta,
    f16* __restrict__ xn)
{
  int row = blockIdx.x;
  int tid = threadIdx.x;
  float4 v = ((const float4*)(x + (size_t)row * DMODEL))[tid];
  float s  = v.x + v.y + v.z + v.w;
  float s2 = v.x*v.x + v.y*v.y + v.z*v.z + v.w*v.w;
  #pragma unroll
  for (int off = 32; off; off >>= 1){ s += __shfl_xor(s, off); s2 += __shfl_xor(s2, off); }
  __shared__ float red[8];
  int wave = tid >> 6, lane = tid & 63;
  if (lane == 0){ red[wave] = s; red[4 + wave] = s2; }
  __syncthreads();
  s  = red[0] + red[1] + red[2] + red[3];
  s2 = red[4] + red[5] + red[6] + red[7];
  float mu  = s * (1.f / DMODEL);
  float var = s2 * (1.f / DMODEL) - mu * mu;
  float rs  = rsqrtf(var + 1e-5f);
  float4 g  = ((const float4*)gamma)[tid];
  float4 be = ((const float4*)beta)[tid];
  f16x4 o;
  o[0] = (f16)((v.x - mu) * rs * g.x + be.x);
  o[1] = (f16)((v.y - mu) * rs * g.y + be.y);
  o[2] = (f16)((v.z - mu) * rs * g.z + be.z);
  o[3] = (f16)((v.w - mu) * rs * g.w + be.w);
  *(f16x4*)(xn + (size_t)row * DMODEL + tid*4) = o;
}

// ------------- Transpose fp32 RxC -> f16 CxR -------------
__global__ __launch_bounds__(256) void transpose_f2h_kernel(const float* __restrict__ in,
    f16* __restrict__ out, int R, int C)
{
  __shared__ float t[32][33];
  int c0 = blockIdx.x * 32, r0 = blockIdx.y * 32;
  int lx = threadIdx.x & 31, ly = threadIdx.x >> 5;
  #pragma unroll
  for (int i = 0; i < 32; i += 8) t[ly + i][lx] = in[(size_t)(r0 + ly + i) * C + c0 + lx];
  __syncthreads();
  #pragma unroll
  for (int i = 0; i < 32; i += 8) out[(size_t)(c0 + ly + i) * R + r0 + lx] = (f16)t[lx][ly + i];
}

// ---------------- QKV GEMM: A[4096,1024]f16 x Bt[3072,1024]f16 -> scatter QKV
// Q is pre-scaled by SCALE_LOG2E (folded out of the attention inner loop).
__global__ __launch_bounds__(256, 3) void gemm_qkv(const f16* __restrict__ A,
    const f16* __restrict__ Bt, f16* __restrict__ Qo, f16* __restrict__ Ko,
    f16* __restrict__ Vo)
{
  __shared__ __align__(16) f16 As[2][128][32];
  __shared__ __align__(16) f16 Bs[2][128][32];
  const int K = DMODEL;
  int bm = blockIdx.y * 128, bn = blockIdx.x * 128;
  int tid = threadIdx.x;
  int wave = tid >> 6, lane = tid & 63, quad = lane >> 4, l15 = lane & 15;
  int mw = (wave >> 1) * 64, nw = (wave & 1) * 64;

  int sr0 = wave*16 + (lane >> 2);          // rows 0..63
  int sr1 = sr0 + 64;                       // rows 64..127 (same &3)
  int sc  = (lane & 3) ^ (sr0 & 3);         // inverse-swizzled source chunk
  const f16* Ag = A  + (size_t)bm * K;
  const f16* Bg = Bt + (size_t)bn * K;
  f16* ldsA0 = &As[0][wave*16     ][0];
  f16* ldsA1 = &As[0][wave*16 + 64][0];
  f16* ldsB0 = &Bs[0][wave*16     ][0];
  f16* ldsB1 = &Bs[0][wave*16 + 64][0];

#define QSTAGE(buf, k0) do{ \
    gload16(Ag + (size_t)sr0 * K + (k0) + sc*8, ldsA0 + (buf)*4096); \
    gload16(Ag + (size_t)sr1 * K + (k0) + sc*8, ldsA1 + (buf)*4096); \
    gload16(Bg + (size_t)sr0 * K + (k0) + sc*8, ldsB0 + (buf)*4096); \
    gload16(Bg + (size_t)sr1 * K + (k0) + sc*8, ldsB1 + (buf)*4096); }while(0)

  f32x4 zero = {0.f, 0.f, 0.f, 0.f};
  f32x4 acc[4][4];
  #pragma unroll
  for (int i = 0; i < 4; i++)
    #pragma unroll
    for (int j = 0; j < 4; j++) acc[i][j] = zero;

  QSTAGE(0, 0);
  const int NS = K / 32;
  for (int it = 0; it < NS; ++it){
    int cur = it & 1;
    asm volatile("s_waitcnt vmcnt(0)" ::: "memory");
    __syncthreads();
    if (it + 1 < NS) QSTAGE(cur ^ 1, (it + 1) * 32);
    int ca = (quad ^ (l15 & 3)) * 8;
    f16x8 af[4], bfr[4];
    #pragma unroll
    for (int i = 0; i < 4; i++) af[i]  = *(const f16x8*)&As[cur][mw + i*16 + l15][ca];
    #pragma unroll
    for (int i = 0; i < 4; i++) bfr[i] = *(const f16x8*)&Bs[cur][nw + i*16 + l15][ca];
    __builtin_amdgcn_s_setprio(1);
    #pragma unroll
    for (int mi = 0; mi < 4; mi++)
      #pragma unroll
      for (int ni = 0; ni < 4; ni++)
        acc[mi][ni] = mfma16h(af[mi], bfr[ni], acc[mi][ni]);
    __builtin_amdgcn_s_setprio(0);
  }
#undef QSTAGE

  #pragma unroll
  for (int mi = 0; mi < 4; mi++){
    #pragma unroll
    for (int ni = 0; ni < 4; ni++){
      int c = bn + nw + ni*16 + l15;
      int which = c >> 10;
      int hc = c & 1023;
      int h = hc >> 6, d = hc & 63;
      if (which == 2){
        // V: 4 regs are 4 consecutive nseq at fixed d -> one f16x4 store
        int r = bm + mw + mi*16 + quad*4;
        int b = r >> 11, nseq = r & 2047;
        size_t bh = (size_t)(b * NH + h);
        f16x4 vv;
        #pragma unroll
        for (int reg = 0; reg < 4; reg++) vv[reg] = (f16)acc[mi][ni][reg];
        *(f16x4*)(Vo + (bh * HD + d) * SEQ + nseq) = vv;
      } else {
        #pragma unroll
        for (int reg = 0; reg < 4; reg++){
          int r = bm + mw + mi*16 + quad*4 + reg;
          float v = acc[mi][ni][reg];
          int b = r >> 11, nseq = r & 2047;
          size_t bh = (size_t)(b * NH + h);
          if (which == 0) Qo[(bh * SEQ + nseq) * HD + d] = (f16)(v * SCALE_LOG2E);
          else            Ko[(bh * SEQ + nseq) * HD + d] = (f16)v;
        }
      }
    }
  }
}

// ---------------- Out GEMM: BM=64, BN=128 -> 512 blocks, fp32 store --------
__global__ __launch_bounds__(256, 4) void gemm_out(const f16* __restrict__ A,
    const f16* __restrict__ Bt, float* __restrict__ C, int M, int N, int K)
{
  __shared__ __align__(16) f16 As[2][64][32];
  __shared__ __align__(16) f16 Bs[2][128][32];
  int bm = blockIdx.y * 64, bn = blockIdx.x * 128;
  int tid = threadIdx.x;
  int wave = tid >> 6, lane = tid & 63, quad = lane >> 4, l15 = lane & 15;
  int mw = (wave >> 1) * 32, nw = (wave & 1) * 64;

  int sr0 = wave*16 + (lane >> 2);          // 0..63
  int sc  = (lane & 3) ^ (sr0 & 3);
  const f16* Ag = A  + (size_t)bm * K;
  const f16* Bg = Bt + (size_t)bn * K;
  f16* ldsA0 = &As[0][wave*16     ][0];
  f16* ldsB0 = &Bs[0][wave*16     ][0];
  f16* ldsB1 = &Bs[0][wave*16 + 64][0];

#define OSTAGE(buf, k0) do{ \
    gload16(Ag + (size_t)sr0 * K + (k0) + sc*8, ldsA0 + (buf)*2048); \
    gload16(Bg + (size_t)sr0 * K + (k0) + sc*8, ldsB0 + (buf)*4096); \
    gload16(Bg + (size_t)(sr0 + 64) * K + (k0) + sc*8, ldsB1 + (buf)*4096); }while(0)

  f32x4 zero = {0.f, 0.f, 0.f, 0.f};
  f32x4 acc[2][4];
  #pragma unroll
  for (int i = 0; i < 2; i++)
    #pragma unroll
    for (int j = 0; j < 4; j++) acc[i][j] = zero;

  OSTAGE(0, 0);
  const int NS = DMODEL / 32;
  for (int it = 0; it < NS; ++it){
    int cur = it & 1;
    asm volatile("s_waitcnt vmcnt(0)" ::: "memory");
    __syncthreads();
    if (it + 1 < NS) OSTAGE(cur ^ 1, (it + 1) * 32);
    int ca = (quad ^ (l15 & 3)) * 8;
    f16x8 af[2], bfr[4];
    #pragma unroll
    for (int i = 0; i < 2; i++) af[i]  = *(const f16x8*)&As[cur][mw + i*16 + l15][ca];
    #pragma unroll
    for (int i = 0; i < 4; i++) bfr[i] = *(const f16x8*)&Bs[cur][nw + i*16 + l15][ca];
    __builtin_amdgcn_s_setprio(1);
    #pragma unroll
    for (int mi = 0; mi < 2; mi++)
      #pragma unroll
      for (int ni = 0; ni < 4; ni++)
        acc[mi][ni] = mfma16h(af[mi], bfr[ni], acc[mi][ni]);
    __builtin_amdgcn_s_setprio(0);
  }
#undef OSTAGE

  #pragma unroll
  for (int mi = 0; mi < 2; mi++)
    #pragma unroll
    for (int ni = 0; ni < 4; ni++)
      #pragma unroll
      for (int reg = 0; reg < 4; reg++){
        int r = bm + mw + mi*16 + quad*4 + reg;
        int c = bn + nw + ni*16 + l15;
        C[(size_t)r * N + c] = acc[mi][ni][reg];
      }
}

// ---------------- Flash attention, 32x32x16 MFMA, in-register P ------------
// Swapped QK^T with mfma_f32_32x32x16_f16: S D-layout col=lane&31=i,
// row(j) = (reg&3)+8*(reg>>2)+4*(lane>>5)  [m74/m101 formula].
// Thread holds a FULL row-half (32 j) of one i -> softmax per-thread scalar
// state; cross-half combine = 1 permlane32_swap. P->PV fragments built
// in-register: 16 cvt_pkrtz + 8 permlane32_swap (T12), no LDS Ps.
// PV: A=Vt-frag (row=d), B=P -> O[d][i]; epilogue bounces O through a
// 72-pitch LDS slab for coalesced 16B global stores.
// K/V double-buffered gload_lds tiles with XOR swizzle (unchanged).
// LDS = 16K(K)+16K(V)+18K(Obounce) = 51200. Grid 512 -> 2 blocks/CU.
__global__ __launch_bounds__(256, 2) void attn_kernel(const f16* __restrict__ Q,
    const f16* __restrict__ Kb, const f16* __restrict__ Vt,
    const float* __restrict__ mask, f16* __restrict__ Ao)
{
  __shared__ __align__(16) f16 KsB[2][64*64];
  __shared__ __align__(16) f16 VsB[2][64*64];
  __shared__ __align__(16) f16 Ob[4][32*72];

  int bh = blockIdx.y; int b = bh >> 4; int h = bh & 15;
  int q0 = blockIdx.x * 128;
  int tid = threadIdx.x;
  int wave = tid >> 6, lane = tid & 63;
  int l31 = lane & 31, hi = lane >> 5;

  // staging geometry: per wave 2 K-insts + 2 V-insts, each 8 rows x 128B
  int rA = (wave*2 + 0)*8 + (lane >> 3);
  int rB = (wave*2 + 1)*8 + (lane >> 3);
  int cp = lane & 7;
  int ccA = cp ^ (rA & 7);
  int ccB = cp ^ (rB & 7);
  const f16* Kg = Kb + (size_t)bh * SEQ * HD;
  const f16* Vg = Vt + (size_t)bh * HD * SEQ;
  f16* ldsKA = &KsB[0][0] + (wave*2 + 0)*8*64;
  f16* ldsKB = &KsB[0][0] + (wave*2 + 1)*8*64;
  f16* ldsVA = &VsB[0][0] + (wave*2 + 0)*8*64;
  f16* ldsVB = &VsB[0][0] + (wave*2 + 1)*8*64;

  // Q B-fragments (pre-scaled by SCALE_LOG2E): lane: Q[i=l31][kt*16+hi*8..+7]
  f16x8 qb[4];
  {
    const f16* qrow = Q + ((size_t)bh * SEQ + q0 + wave*32 + l31) * HD + hi*8;
    #pragma unroll
    for (int kt = 0; kt < 4; kt++) qb[kt] = *(const f16x8*)(qrow + kt*16);
  }

  // per-thread mask row i = q0 + wave*32 + l31
  const float* mrow = mask + ((size_t)b * SEQ + q0 + wave*32 + l31) * SEQ;

  // prologue: stage tile 0 into buffer 0
  gload16(Kg + (size_t)(0 + rA)*HD + ccA*8, ldsKA);
  gload16(Kg + (size_t)(0 + rB)*HD + ccB*8, ldsKB);
  gload16(Vg + (size_t)rA*SEQ + 0 + ccA*8, ldsVA);
  gload16(Vg + (size_t)rB*SEQ + 0 + ccB*8, ldsVB);

  f32x16 O0, O1;
  #pragma unroll
  for (int i = 0; i < 16; i++){ O0[i] = 0.f; O1[i] = 0.f; }
  float mrun = NEG_BIG, lrun = 0.f;

  const int NT = SEQ / 64;
  for (int it = 0; it < NT; ++it){
    int cur = it & 1;
    int j0 = it * 64;
    asm volatile("s_waitcnt vmcnt(0)" ::: "memory");
    __syncthreads();
    if (it + 1 < NT){
      int nb = cur ^ 1;
      int j0n = j0 + 64;
      gload16(Kg + (size_t)(j0n + rA)*HD + ccA*8, ldsKA + nb*4096);
      gload16(Kg + (size_t)(j0n + rB)*HD + ccB*8, ldsKB + nb*4096);
      gload16(Vg + (size_t)rA*SEQ + j0n + ccA*8, ldsVA + nb*4096);
      gload16(Vg + (size_t)rB*SEQ + j0n + ccB*8, ldsVB + nb*4096);
    }
    const f16* Ksc = &KsB[cur][0];
    const f16* Vsc = &VsB[cur][0];

    // mask loads early (latency hides under QK MFMAs)
    float4 mv0[4], mv1[4];
    #pragma unroll
    for (int g = 0; g < 4; g++){
      mv0[g] = *(const float4*)(mrow + j0 +      g*8 + hi*4);
      mv1[g] = *(const float4*)(mrow + j0 + 32 + g*8 + hi*4);
    }

    // ---- QK^T: A = K-frag (row=j), B = Q (col=i); acc over d in 4 steps ----
    f32x16 s0, s1;
    #pragma unroll
    for (int i = 0; i < 16; i++){ s0[i] = 0.f; s1[i] = 0.f; }
    __builtin_amdgcn_s_setprio(1);
    #pragma unroll
    for (int kt = 0; kt < 4; kt++){
      int c = ((kt*2 + hi) ^ (l31 & 7)) * 8;
      f16x8 ka0 = *(const f16x8*)&Ksc[ l31      *64 + c];
      f16x8 ka1 = *(const f16x8*)&Ksc[(32 + l31)*64 + c];
      s0 = mfma32h(ka0, qb[kt], s0);
      s1 = mfma32h(ka1, qb[kt], s1);
    }
    __builtin_amdgcn_s_setprio(0);

    // ---- add mask (Q pre-scaled: S already in log2-scaled domain) ----
    float p0[16], p1[16];
    #pragma unroll
    for (int g = 0; g < 4; g++){
      p0[g*4+0] = fmaf(mv0[g].x, SCALE_LOG2E, s0[g*4+0]);
      p0[g*4+1] = fmaf(mv0[g].y, SCALE_LOG2E, s0[g*4+1]);
      p0[g*4+2] = fmaf(mv0[g].z, SCALE_LOG2E, s0[g*4+2]);
      p0[g*4+3] = fmaf(mv0[g].w, SCALE_LOG2E, s0[g*4+3]);
      p1[g*4+0] = fmaf(mv1[g].x, SCALE_LOG2E, s1[g*4+0]);
      p1[g*4+1] = fmaf(mv1[g].y, SCALE_LOG2E, s1[g*4+1]);
      p1[g*4+2] = fmaf(mv1[g].z, SCALE_LOG2E, s1[g*4+2]);
      p1[g*4+3] = fmaf(mv1[g].w, SCALE_LOG2E, s1[g*4+3]);
    }

    // ---- row max: in-thread tree over 32 + 1 permlane swap ----
    float t0 = fmaxf(fmaxf(fmaxf(p0[0],p0[1]),fmaxf(p0[2],p0[3])),
                     fmaxf(fmaxf(p0[4],p0[5]),fmaxf(p0[6],p0[7])));
    float t1 = fmaxf(fmaxf(fmaxf(p0[8],p0[9]),fmaxf(p0[10],p0[11])),
                     fmaxf(fmaxf(p0[12],p0[13]),fmaxf(p0[14],p0[15])));
    float t2 = fmaxf(fmaxf(fmaxf(p1[0],p1[1]),fmaxf(p1[2],p1[3])),
                     fmaxf(fmaxf(p1[4],p1[5]),fmaxf(p1[6],p1[7])));
    float t3 = fmaxf(fmaxf(fmaxf(p1[8],p1[9]),fmaxf(p1[10],p1[11])),
                     fmaxf(fmaxf(p1[12],p1[13]),fmaxf(p1[14],p1[15])));
    float tmax = fmaxf(fmaxf(t0, t1), fmaxf(t2, t3));
    {
      u32x2 r = pswap(__float_as_uint(tmax), __float_as_uint(tmax));
      tmax = fmaxf(__uint_as_float(r[0]), __uint_as_float(r[1]));
    }

    // ---- defer-max rescale (THR=8 log2 -> P <= 256, f16-safe); alpha is
    // per-thread scalar (O column = own i) ----
    if (__any(tmax > mrun + 8.f)){
      float nm = fmaxf(mrun, tmax);
      float alpha = exp2f(mrun - nm);
      mrun = nm;
      lrun *= alpha;
      #pragma unroll
      for (int i = 0; i < 16; i++){ O0[i] *= alpha; O1[i] *= alpha; }
    }

    // ---- exp + per-thread partial sum ----
    float ps = 0.f;
    #pragma unroll
    for (int i = 0; i < 16; i++){
      p0[i] = exp2f(p0[i] - mrun); ps += p0[i];
      p1[i] = exp2f(p1[i] - mrun); ps += p1[i];
    }
    lrun += ps;

    // ---- P -> B-fragments in-register: cvt_pkrtz + permlane32_swap (T12) --
    unsigned u0[4][2], u1[4][2];
    #pragma unroll
    for (int g = 0; g < 4; g++){
      u0[g][0] = pk16(p0[g*4+0], p0[g*4+1]);
      u0[g][1] = pk16(p0[g*4+2], p0[g*4+3]);
      u1[g][0] = pk16(p1[g*4+0], p1[g*4+1]);
      u1[g][1] = pk16(p1[g*4+2], p1[g*4+3]);
    }
    f16x8 pb[4];
    #pragma unroll
    for (int m = 0; m < 2; m++){
      u32x2 r0 = pswap(u0[2*m][0], u0[2*m+1][0]);
      u32x2 r1 = pswap(u0[2*m][1], u0[2*m+1][1]);
      union { unsigned u[4]; f16x8 v; } w;
      w.u[0] = r0[0]; w.u[1] = r1[0]; w.u[2] = r0[1]; w.u[3] = r1[1];
      pb[m] = w.v;
      r0 = pswap(u1[2*m][0], u1[2*m+1][0]);
      r1 = pswap(u1[2*m][1], u1[2*m+1][1]);
      w.u[0] = r0[0]; w.u[1] = r1[0]; w.u[2] = r0[1]; w.u[3] = r1[1];
      pb[2 + m] = w.v;
    }

    // ---- PV: A = Vt-frag (row=d), B = P (col=i) -> O[d][i] ----
    __builtin_amdgcn_s_setprio(1);
    #pragma unroll
    for (int jt = 0; jt < 4; jt++){
      int c = ((jt*2 + hi) ^ (l31 & 7)) * 8;
      f16x8 va0 = *(const f16x8*)&Vsc[ l31      *64 + c];
      f16x8 va1 = *(const f16x8*)&Vsc[(32 + l31)*64 + c];
      O0 = mfma32h(va0, pb[jt], O0);
      O1 = mfma32h(va1, pb[jt], O1);
    }
    __builtin_amdgcn_s_setprio(0);
  }

  // ---- epilogue: combine sum across lane-halves (1 swap), normalize,
  // bounce O[d][i] -> [i][d] through LDS, coalesced 16B stores ----
  {
    u32x2 r = pswap(__float_as_uint(lrun), __float_as_uint(lrun));
    lrun = __uint_as_float(r[0]) + __uint_as_float(r[1]);
  }
  float inv = 1.0f / lrun;
  f16* slab = &Ob[wave][0];
  #pragma unroll
  for (int g = 0; g < 4; g++){
    f16x4 w0, w1;
    #pragma unroll
    for (int rg = 0; rg < 4; rg++){
      w0[rg] = (f16)(O0[g*4+rg] * inv);
      w1[rg] = (f16)(O1[g*4+rg] * inv);
    }
    *(f16x4*)&slab[l31*72 +      g*8 + hi*4] = w0;
    *(f16x4*)&slab[l31*72 + 32 + g*8 + hi*4] = w1;
  }
  // read back rows of [i][d] and store coalesced
  int ir  = lane >> 3;          // 0..7
  int c16 = lane & 7;           // 16B chunk within row
  #pragma unroll
  for (int rr = 0; rr < 4; rr++){
    int i = rr*8 + ir;
    f16x8 ov = *(const f16x8*)&slab[i*72 + c16*8];
    *(f16x8*)(Ao + ((size_t)(b * SEQ + q0 + wave*32 + i)) * DMODEL + h * HD + c16*8) = ov;
  }
}

// ---------------- launch ----------------
// OUTPUT IS FP32. ws (>=48 MiB verified by probe):
//   xn f16 @0 (Ao alias after QKV) | Qb @8M (WoutT alias after attn)
//   Kb @16M | Vt @24M | WqkvT @32M (6MB)
extern "C" void kernel_launch(void* const* d_in, const int* in_sizes, int n_in,
                              void* d_out, int out_size, void* d_ws, size_t ws_size,
                              hipStream_t stream)
{
  (void)in_sizes; (void)n_in; (void)out_size; (void)ws_size;
  const float* x     = (const float*)d_in[0];
  const float* m     = (const float*)d_in[1];
  const float* gamma = (const float*)d_in[2];
  const float* beta  = (const float*)d_in[3];
  const float* Wqkv  = (const float*)d_in[4];
  const float* Wout  = (const float*)d_in[5];
  float* out = (float*)d_out;

  char* ws = (char*)d_ws;
  f16* xn    = (f16*)(ws + 0);
  f16* Ao    = (f16*)(ws + 0);            // alias: xn dead after gemm_qkv
  f16* Qb    = (f16*)(ws + 8388608);
  f16* WoutT = (f16*)(ws + 8388608);      // alias: Qb dead after attn
  f16* Kbuf  = (f16*)(ws + 16777216);
  f16* Vtb   = (f16*)(ws + 25165824);
  f16* WqkvT = (f16*)(ws + 33554432);

  ln_kernel<<<ROWS, 256, 0, stream>>>(x, gamma, beta, xn);
  transpose_f2h_kernel<<<dim3(NQKV/32, DMODEL/32), 256, 0, stream>>>(Wqkv, WqkvT, DMODEL, NQKV);
  gemm_qkv<<<dim3(NQKV/128, ROWS/128), 256, 0, stream>>>(xn, WqkvT, Qb, Kbuf, Vtb);
  attn_kernel<<<dim3(SEQ/128, BATCH*NH), 256, 0, stream>>>(Qb, Kbuf, Vtb, m, Ao);
  transpose_f2h_kernel<<<dim3(DMODEL/32, DMODEL/32), 256, 0, stream>>>(Wout, WoutT, DMODEL, DMODEL);
  gemm_out<<<dim3(DMODEL/128, ROWS/64), 256, 0, stream>>>(Ao, WoutT, out, ROWS, DMODEL, DMODEL);
}

// Round 8
// 240.611 us; speedup vs baseline: 1.0745x; 1.0668x over previous
//
#include <hip/hip_runtime.h>
#include <hip/hip_bf16.h>
#include <math.h>

typedef _Float16 f16;
typedef __fp16 hf2 __attribute__((ext_vector_type(2)));
typedef _Float16 f16x4 __attribute__((ext_vector_type(4)));
typedef _Float16 f16x8 __attribute__((ext_vector_type(8)));
typedef float f32x4 __attribute__((ext_vector_type(4)));
typedef float f32x16 __attribute__((ext_vector_type(16)));
typedef unsigned int u32x2 __attribute__((ext_vector_type(2)));

#define HD 64
#define NH 16
#define BATCH 2
#define SEQ 2048
#define DMODEL 1024
#define NQKV 3072
#define ROWS 4096
#define NEG_BIG (-1.0e30f)
// 0.125 * log2(e): softmax in base-2 domain; folded into Q at gemm_qkv epilogue
#define SCALE_LOG2E 0.18033688011112042f

__device__ __forceinline__ f32x4 mfma16h(f16x8 a, f16x8 b, f32x4 c){
  return __builtin_amdgcn_mfma_f32_16x16x32_f16(a, b, c, 0, 0, 0);
}
__device__ __forceinline__ f32x16 mfma32h(f16x8 a, f16x8 b, f32x16 c){
  return __builtin_amdgcn_mfma_f32_32x32x16_f16(a, b, c, 0, 0, 0);
}
__device__ __forceinline__ u32x2 pswap(unsigned a, unsigned b){
  return __builtin_amdgcn_permlane32_swap(a, b, false, false);
}
__device__ __forceinline__ unsigned pk16(float a, float b){
  hf2 r = __builtin_amdgcn_cvt_pkrtz(a, b);
  return __builtin_bit_cast(unsigned, r);
}

// global -> LDS async copy, 16B per lane, dest = wave-uniform base + lane*16
__device__ __forceinline__ void gload16(const f16* g, f16* l){
  __builtin_amdgcn_global_load_lds(
      (const __attribute__((address_space(1))) unsigned int*)(g),
      (__attribute__((address_space(3))) unsigned int*)(l), 16, 0, 0);
}
__device__ __forceinline__ void gload16f(const float* g, float* l){
  __builtin_amdgcn_global_load_lds(
      (const __attribute__((address_space(1))) unsigned int*)(g),
      (__attribute__((address_space(3))) unsigned int*)(l), 16, 0, 0);
}

// ---------------- LayerNorm: fp32 in, f16 out (float4 vectorized) ----------
__global__ __launch_bounds__(256) void ln_kernel(const float* __restrict__ x,
    const float* __restrict__ gamma, const float* __restrict__ beta,
    f16* __restrict__ xn)
{
  int row = blockIdx.x;
  int tid = threadIdx.x;
  float4 v = ((const float4*)(x + (size_t)row * DMODEL))[tid];
  float s  = v.x + v.y + v.z + v.w;
  float s2 = v.x*v.x + v.y*v.y + v.z*v.z + v.w*v.w;
  #pragma unroll
  for (int off = 32; off; off >>= 1){ s += __shfl_xor(s, off); s2 += __shfl_xor(s2, off); }
  __shared__ float red[8];
  int wave = tid >> 6, lane = tid & 63;
  if (lane == 0){ red[wave] = s; red[4 + wave] = s2; }
  __syncthreads();
  s  = red[0] + red[1] + red[2] + red[3];
  s2 = red[4] + red[5] + red[6] + red[7];
  float mu  = s * (1.f / DMODEL);
  float var = s2 * (1.f / DMODEL) - mu * mu;
  float rs  = rsqrtf(var + 1e-5f);
  float4 g  = ((const float4*)gamma)[tid];
  float4 be = ((const float4*)beta)[tid];
  f16x4 o;
  o[0] = (f16)((v.x - mu) * rs * g.x + be.x);
  o[1] = (f16)((v.y - mu) * rs * g.y + be.y);
  o[2] = (f16)((v.z - mu) * rs * g.z + be.z);
  o[3] = (f16)((v.w - mu) * rs * g.w + be.w);
  *(f16x4*)(xn + (size_t)row * DMODEL + tid*4) = o;
}

// ------------- Transpose fp32 RxC -> f16 CxR -------------
__global__ __launch_bounds__(256) void transpose_f2h_kernel(const float* __restrict__ in,
    f16* __restrict__ out, int R, int C)
{
  __shared__ float t[32][33];
  int c0 = blockIdx.x * 32, r0 = blockIdx.y * 32;
  int lx = threadIdx.x & 31, ly = threadIdx.x >> 5;
  #pragma unroll
  for (int i = 0; i < 32; i += 8) t[ly + i][lx] = in[(size_t)(r0 + ly + i) * C + c0 + lx];
  __syncthreads();
  #pragma unroll
  for (int i = 0; i < 32; i += 8) out[(size_t)(c0 + ly + i) * R + r0 + lx] = (f16)t[lx][ly + i];
}

// ---------------- QKV GEMM: A[4096,1024]f16 x Bt[3072,1024]f16 -> scatter QKV
// Q is pre-scaled by SCALE_LOG2E (folded out of the attention inner loop).
__global__ __launch_bounds__(256, 3) void gemm_qkv(const f16* __restrict__ A,
    const f16* __restrict__ Bt, f16* __restrict__ Qo, f16* __restrict__ Ko,
    f16* __restrict__ Vo)
{
  __shared__ __align__(16) f16 As[2][128][32];
  __shared__ __align__(16) f16 Bs[2][128][32];
  const int K = DMODEL;
  int bm = blockIdx.y * 128, bn = blockIdx.x * 128;
  int tid = threadIdx.x;
  int wave = tid >> 6, lane = tid & 63, quad = lane >> 4, l15 = lane & 15;
  int mw = (wave >> 1) * 64, nw = (wave & 1) * 64;

  int sr0 = wave*16 + (lane >> 2);          // rows 0..63
  int sr1 = sr0 + 64;                       // rows 64..127 (same &3)
  int sc  = (lane & 3) ^ (sr0 & 3);         // inverse-swizzled source chunk
  const f16* Ag = A  + (size_t)bm * K;
  const f16* Bg = Bt + (size_t)bn * K;
  f16* ldsA0 = &As[0][wave*16     ][0];
  f16* ldsA1 = &As[0][wave*16 + 64][0];
  f16* ldsB0 = &Bs[0][wave*16     ][0];
  f16* ldsB1 = &Bs[0][wave*16 + 64][0];

#define QSTAGE(buf, k0) do{ \
    gload16(Ag + (size_t)sr0 * K + (k0) + sc*8, ldsA0 + (buf)*4096); \
    gload16(Ag + (size_t)sr1 * K + (k0) + sc*8, ldsA1 + (buf)*4096); \
    gload16(Bg + (size_t)sr0 * K + (k0) + sc*8, ldsB0 + (buf)*4096); \
    gload16(Bg + (size_t)sr1 * K + (k0) + sc*8, ldsB1 + (buf)*4096); }while(0)

  f32x4 zero = {0.f, 0.f, 0.f, 0.f};
  f32x4 acc[4][4];
  #pragma unroll
  for (int i = 0; i < 4; i++)
    #pragma unroll
    for (int j = 0; j < 4; j++) acc[i][j] = zero;

  QSTAGE(0, 0);
  const int NS = K / 32;
  for (int it = 0; it < NS; ++it){
    int cur = it & 1;
    asm volatile("s_waitcnt vmcnt(0)" ::: "memory");
    __syncthreads();
    if (it + 1 < NS) QSTAGE(cur ^ 1, (it + 1) * 32);
    int ca = (quad ^ (l15 & 3)) * 8;
    f16x8 af[4], bfr[4];
    #pragma unroll
    for (int i = 0; i < 4; i++) af[i]  = *(const f16x8*)&As[cur][mw + i*16 + l15][ca];
    #pragma unroll
    for (int i = 0; i < 4; i++) bfr[i] = *(const f16x8*)&Bs[cur][nw + i*16 + l15][ca];
    __builtin_amdgcn_s_setprio(1);
    #pragma unroll
    for (int mi = 0; mi < 4; mi++)
      #pragma unroll
      for (int ni = 0; ni < 4; ni++)
        acc[mi][ni] = mfma16h(af[mi], bfr[ni], acc[mi][ni]);
    __builtin_amdgcn_s_setprio(0);
  }
#undef QSTAGE

  #pragma unroll
  for (int mi = 0; mi < 4; mi++){
    #pragma unroll
    for (int ni = 0; ni < 4; ni++){
      int c = bn + nw + ni*16 + l15;
      int which = c >> 10;
      int hc = c & 1023;
      int h = hc >> 6, d = hc & 63;
      if (which == 2){
        // V: 4 regs are 4 consecutive nseq at fixed d -> one f16x4 store
        int r = bm + mw + mi*16 + quad*4;
        int b = r >> 11, nseq = r & 2047;
        size_t bh = (size_t)(b * NH + h);
        f16x4 vv;
        #pragma unroll
        for (int reg = 0; reg < 4; reg++) vv[reg] = (f16)acc[mi][ni][reg];
        *(f16x4*)(Vo + (bh * HD + d) * SEQ + nseq) = vv;
      } else {
        #pragma unroll
        for (int reg = 0; reg < 4; reg++){
          int r = bm + mw + mi*16 + quad*4 + reg;
          float v = acc[mi][ni][reg];
          int b = r >> 11, nseq = r & 2047;
          size_t bh = (size_t)(b * NH + h);
          if (which == 0) Qo[(bh * SEQ + nseq) * HD + d] = (f16)(v * SCALE_LOG2E);
          else            Ko[(bh * SEQ + nseq) * HD + d] = (f16)v;
        }
      }
    }
  }
}

// ---------------- Out GEMM: BM=64, BN=128 -> 512 blocks, fp32 store --------
__global__ __launch_bounds__(256, 4) void gemm_out(const f16* __restrict__ A,
    const f16* __restrict__ Bt, float* __restrict__ C, int M, int N, int K)
{
  __shared__ __align__(16) f16 As[2][64][32];
  __shared__ __align__(16) f16 Bs[2][128][32];
  int bm = blockIdx.y * 64, bn = blockIdx.x * 128;
  int tid = threadIdx.x;
  int wave = tid >> 6, lane = tid & 63, quad = lane >> 4, l15 = lane & 15;
  int mw = (wave >> 1) * 32, nw = (wave & 1) * 64;

  int sr0 = wave*16 + (lane >> 2);          // 0..63
  int sc  = (lane & 3) ^ (sr0 & 3);
  const f16* Ag = A  + (size_t)bm * K;
  const f16* Bg = Bt + (size_t)bn * K;
  f16* ldsA0 = &As[0][wave*16     ][0];
  f16* ldsB0 = &Bs[0][wave*16     ][0];
  f16* ldsB1 = &Bs[0][wave*16 + 64][0];

#define OSTAGE(buf, k0) do{ \
    gload16(Ag + (size_t)sr0 * K + (k0) + sc*8, ldsA0 + (buf)*2048); \
    gload16(Bg + (size_t)sr0 * K + (k0) + sc*8, ldsB0 + (buf)*4096); \
    gload16(Bg + (size_t)(sr0 + 64) * K + (k0) + sc*8, ldsB1 + (buf)*4096); }while(0)

  f32x4 zero = {0.f, 0.f, 0.f, 0.f};
  f32x4 acc[2][4];
  #pragma unroll
  for (int i = 0; i < 2; i++)
    #pragma unroll
    for (int j = 0; j < 4; j++) acc[i][j] = zero;

  OSTAGE(0, 0);
  const int NS = DMODEL / 32;
  for (int it = 0; it < NS; ++it){
    int cur = it & 1;
    asm volatile("s_waitcnt vmcnt(0)" ::: "memory");
    __syncthreads();
    if (it + 1 < NS) OSTAGE(cur ^ 1, (it + 1) * 32);
    int ca = (quad ^ (l15 & 3)) * 8;
    f16x8 af[2], bfr[4];
    #pragma unroll
    for (int i = 0; i < 2; i++) af[i]  = *(const f16x8*)&As[cur][mw + i*16 + l15][ca];
    #pragma unroll
    for (int i = 0; i < 4; i++) bfr[i] = *(const f16x8*)&Bs[cur][nw + i*16 + l15][ca];
    __builtin_amdgcn_s_setprio(1);
    #pragma unroll
    for (int mi = 0; mi < 2; mi++)
      #pragma unroll
      for (int ni = 0; ni < 4; ni++)
        acc[mi][ni] = mfma16h(af[mi], bfr[ni], acc[mi][ni]);
    __builtin_amdgcn_s_setprio(0);
  }
#undef OSTAGE

  #pragma unroll
  for (int mi = 0; mi < 2; mi++)
    #pragma unroll
    for (int ni = 0; ni < 4; ni++)
      #pragma unroll
      for (int reg = 0; reg < 4; reg++){
        int r = bm + mw + mi*16 + quad*4 + reg;
        int c = bn + nw + ni*16 + l15;
        C[(size_t)r * N + c] = acc[mi][ni][reg];
      }
}

// ---------------- Flash attention, 32x32x16 MFMA, in-register P ------------
// R7 structure + COALESCED MASK STAGING: mask tile staged global->LDS via
// global_load_lds (8 instrs/wave = 1KB coalesced each, replacing 8 float4
// loads that were 64-way scattered = 512 transactions/wave-iter — the
// invariant ~110µs wall across R2/R4/R5/R7). Per-wave private fp32 slab
// [32 rows][16 chunks], chunk-swizzled slot = c ^ (r&15); latency hidden
// under QK via counted vmcnt(4) (mask issued before the 4 K/V prefetch).
// Epilogue O-bounce aliases the mask slab. LDS = 16K(K)+16K(V)+32K(mask)
// = 65536 -> 2 blocks/CU.
__global__ __launch_bounds__(256, 2) void attn_kernel(const f16* __restrict__ Q,
    const f16* __restrict__ Kb, const f16* __restrict__ Vt,
    const float* __restrict__ mask, f16* __restrict__ Ao)
{
  __shared__ __align__(16) f16 KsB[2][64*64];
  __shared__ __align__(16) f16 VsB[2][64*64];
  __shared__ __align__(16) float Msk[4][2048];   // per-wave 32x64 fp32, swizzled

  int bh = blockIdx.y; int b = bh >> 4; int h = bh & 15;
  int q0 = blockIdx.x * 128;
  int tid = threadIdx.x;
  int wave = tid >> 6, lane = tid & 63;
  int l31 = lane & 31, hi = lane >> 5;

  // K/V staging geometry: per wave 2 K-insts + 2 V-insts, each 8 rows x 128B
  int rA = (wave*2 + 0)*8 + (lane >> 3);
  int rB = (wave*2 + 1)*8 + (lane >> 3);
  int cp = lane & 7;
  int ccA = cp ^ (rA & 7);
  int ccB = cp ^ (rB & 7);
  const f16* Kg = Kb + (size_t)bh * SEQ * HD;
  const f16* Vg = Vt + (size_t)bh * HD * SEQ;
  f16* ldsKA = &KsB[0][0] + (wave*2 + 0)*8*64;
  f16* ldsKB = &KsB[0][0] + (wave*2 + 1)*8*64;
  f16* ldsVA = &VsB[0][0] + (wave*2 + 0)*8*64;
  f16* ldsVB = &VsB[0][0] + (wave*2 + 1)*8*64;

  // mask staging geometry: 8 gload16f per iter; instr t covers rows 4t..4t+3
  float* mslab = &Msk[wave][0];
  const float* Mg = mask + ((size_t)b * SEQ + q0 + wave*32) * SEQ;
  int mrl = lane >> 4;          // row-in-group 0..3
  int msl = lane & 15;          // dest slot 0..15

  // Q B-fragments (pre-scaled by SCALE_LOG2E): lane: Q[i=l31][kt*16+hi*8..+7]
  f16x8 qb[4];
  {
    const f16* qrow = Q + ((size_t)bh * SEQ + q0 + wave*32 + l31) * HD + hi*8;
    #pragma unroll
    for (int kt = 0; kt < 4; kt++) qb[kt] = *(const f16x8*)(qrow + kt*16);
  }

  // prologue: stage K/V tile 0 into buffer 0
  gload16(Kg + (size_t)(0 + rA)*HD + ccA*8, ldsKA);
  gload16(Kg + (size_t)(0 + rB)*HD + ccB*8, ldsKB);
  gload16(Vg + (size_t)rA*SEQ + 0 + ccA*8, ldsVA);
  gload16(Vg + (size_t)rB*SEQ + 0 + ccB*8, ldsVB);

  f32x16 O0, O1;
  #pragma unroll
  for (int i = 0; i < 16; i++){ O0[i] = 0.f; O1[i] = 0.f; }
  float mrun = NEG_BIG, lrun = 0.f;

  const int NT = SEQ / 64;
  for (int it = 0; it < NT; ++it){
    int cur = it & 1;
    int j0 = it * 64;
    asm volatile("s_waitcnt vmcnt(0)" ::: "memory");   // K/V tile landed
    __syncthreads();

    // mask stage for THIS iter (issued first -> drained by vmcnt(4))
    #pragma unroll
    for (int t = 0; t < 8; t++){
      int r = t*4 + mrl;
      gload16f(Mg + (size_t)r * SEQ + j0 + ((msl ^ (r & 15)) << 2), mslab + t*256);
    }
    // K/V prefetch for next tile (always issued; wraps on last iter)
    {
      int nb = cur ^ 1;
      int jn = (j0 + 64) & (SEQ - 1);
      gload16(Kg + (size_t)(jn + rA)*HD + ccA*8, ldsKA + nb*4096);
      gload16(Kg + (size_t)(jn + rB)*HD + ccB*8, ldsKB + nb*4096);
      gload16(Vg + (size_t)rA*SEQ + jn + ccA*8, ldsVA + nb*4096);
      gload16(Vg + (size_t)rB*SEQ + jn + ccB*8, ldsVB + nb*4096);
    }
    const f16* Ksc = &KsB[cur][0];
    const f16* Vsc = &VsB[cur][0];

    // ---- QK^T: A = K-frag (row=j), B = Q (col=i); acc over d in 4 steps ----
    f32x16 s0, s1;
    #pragma unroll
    for (int i = 0; i < 16; i++){ s0[i] = 0.f; s1[i] = 0.f; }
    __builtin_amdgcn_s_setprio(1);
    #pragma unroll
    for (int kt = 0; kt < 4; kt++){
      int c = ((kt*2 + hi) ^ (l31 & 7)) * 8;
      f16x8 ka0 = *(const f16x8*)&Ksc[ l31      *64 + c];
      f16x8 ka1 = *(const f16x8*)&Ksc[(32 + l31)*64 + c];
      s0 = mfma32h(ka0, qb[kt], s0);
      s1 = mfma32h(ka1, qb[kt], s1);
    }
    __builtin_amdgcn_s_setprio(0);

    // ---- mask landed (only the 4 K/V prefetch may remain in flight) ----
    asm volatile("s_waitcnt vmcnt(4)" ::: "memory");

    // ---- read mask from LDS (swizzled) + add (Q pre-scaled) ----
    float p0[16], p1[16];
    #pragma unroll
    for (int g = 0; g < 4; g++){
      float4 mv0 = *(const float4*)&Msk[wave][l31*64 + ((( g*2 + hi) ^ (l31 & 15)) << 2)];
      float4 mv1 = *(const float4*)&Msk[wave][l31*64 + (((8 + g*2 + hi) ^ (l31 & 15)) << 2)];
      p0[g*4+0] = fmaf(mv0.x, SCALE_LOG2E, s0[g*4+0]);
      p0[g*4+1] = fmaf(mv0.y, SCALE_LOG2E, s0[g*4+1]);
      p0[g*4+2] = fmaf(mv0.z, SCALE_LOG2E, s0[g*4+2]);
      p0[g*4+3] = fmaf(mv0.w, SCALE_LOG2E, s0[g*4+3]);
      p1[g*4+0] = fmaf(mv1.x, SCALE_LOG2E, s1[g*4+0]);
      p1[g*4+1] = fmaf(mv1.y, SCALE_LOG2E, s1[g*4+1]);
      p1[g*4+2] = fmaf(mv1.z, SCALE_LOG2E, s1[g*4+2]);
      p1[g*4+3] = fmaf(mv1.w, SCALE_LOG2E, s1[g*4+3]);
    }

    // ---- row max: in-thread tree over 32 + 1 permlane swap ----
    float t0 = fmaxf(fmaxf(fmaxf(p0[0],p0[1]),fmaxf(p0[2],p0[3])),
                     fmaxf(fmaxf(p0[4],p0[5]),fmaxf(p0[6],p0[7])));
    float t1 = fmaxf(fmaxf(fmaxf(p0[8],p0[9]),fmaxf(p0[10],p0[11])),
                     fmaxf(fmaxf(p0[12],p0[13]),fmaxf(p0[14],p0[15])));
    float t2 = fmaxf(fmaxf(fmaxf(p1[0],p1[1]),fmaxf(p1[2],p1[3])),
                     fmaxf(fmaxf(p1[4],p1[5]),fmaxf(p1[6],p1[7])));
    float t3 = fmaxf(fmaxf(fmaxf(p1[8],p1[9]),fmaxf(p1[10],p1[11])),
                     fmaxf(fmaxf(p1[12],p1[13]),fmaxf(p1[14],p1[15])));
    float tmax = fmaxf(fmaxf(t0, t1), fmaxf(t2, t3));
    {
      u32x2 r = pswap(__float_as_uint(tmax), __float_as_uint(tmax));
      tmax = fmaxf(__uint_as_float(r[0]), __uint_as_float(r[1]));
    }

    // ---- defer-max rescale (THR=8 log2 -> P <= 256, f16-safe) ----
    if (__any(tmax > mrun + 8.f)){
      float nm = fmaxf(mrun, tmax);
      float alpha = exp2f(mrun - nm);
      mrun = nm;
      lrun *= alpha;
      #pragma unroll
      for (int i = 0; i < 16; i++){ O0[i] *= alpha; O1[i] *= alpha; }
    }

    // ---- exp + per-thread partial sum ----
    float ps = 0.f;
    #pragma unroll
    for (int i = 0; i < 16; i++){
      p0[i] = exp2f(p0[i] - mrun); ps += p0[i];
      p1[i] = exp2f(p1[i] - mrun); ps += p1[i];
    }
    lrun += ps;

    // ---- P -> B-fragments in-register: cvt_pkrtz + permlane32_swap (T12) --
    unsigned u0[4][2], u1[4][2];
    #pragma unroll
    for (int g = 0; g < 4; g++){
      u0[g][0] = pk16(p0[g*4+0], p0[g*4+1]);
      u0[g][1] = pk16(p0[g*4+2], p0[g*4+3]);
      u1[g][0] = pk16(p1[g*4+0], p1[g*4+1]);
      u1[g][1] = pk16(p1[g*4+2], p1[g*4+3]);
    }
    f16x8 pb[4];
    #pragma unroll
    for (int m = 0; m < 2; m++){
      u32x2 r0 = pswap(u0[2*m][0], u0[2*m+1][0]);
      u32x2 r1 = pswap(u0[2*m][1], u0[2*m+1][1]);
      union { unsigned u[4]; f16x8 v; } w;
      w.u[0] = r0[0]; w.u[1] = r1[0]; w.u[2] = r0[1]; w.u[3] = r1[1];
      pb[m] = w.v;
      r0 = pswap(u1[2*m][0], u1[2*m+1][0]);
      r1 = pswap(u1[2*m][1], u1[2*m+1][1]);
      w.u[0] = r0[0]; w.u[1] = r1[0]; w.u[2] = r0[1]; w.u[3] = r1[1];
      pb[2 + m] = w.v;
    }

    // ---- PV: A = Vt-frag (row=d), B = P (col=i) -> O[d][i] ----
    __builtin_amdgcn_s_setprio(1);
    #pragma unroll
    for (int jt = 0; jt < 4; jt++){
      int c = ((jt*2 + hi) ^ (l31 & 7)) * 8;
      f16x8 va0 = *(const f16x8*)&Vsc[ l31      *64 + c];
      f16x8 va1 = *(const f16x8*)&Vsc[(32 + l31)*64 + c];
      O0 = mfma32h(va0, pb[jt], O0);
      O1 = mfma32h(va1, pb[jt], O1);
    }
    __builtin_amdgcn_s_setprio(0);
  }

  // ---- epilogue: combine sum across lane-halves (1 swap), normalize,
  // bounce O[d][i] -> [i][d] through the (dead) mask slab, coalesced stores --
  {
    u32x2 r = pswap(__float_as_uint(lrun), __float_as_uint(lrun));
    lrun = __uint_as_float(r[0]) + __uint_as_float(r[1]);
  }
  float inv = 1.0f / lrun;
  f16* slab = (f16*)&Msk[wave][0];      // 8KB per wave, mask dead after loop
  #pragma unroll
  for (int g = 0; g < 4; g++){
    f16x4 w0, w1;
    #pragma unroll
    for (int rg = 0; rg < 4; rg++){
      w0[rg] = (f16)(O0[g*4+rg] * inv);
      w1[rg] = (f16)(O1[g*4+rg] * inv);
    }
    *(f16x4*)&slab[l31*72 +      g*8 + hi*4] = w0;
    *(f16x4*)&slab[l31*72 + 32 + g*8 + hi*4] = w1;
  }
  // read back rows of [i][d] and store coalesced
  int ir  = lane >> 3;          // 0..7
  int c16 = lane & 7;           // 16B chunk within row
  #pragma unroll
  for (int rr = 0; rr < 4; rr++){
    int i = rr*8 + ir;
    f16x8 ov = *(const f16x8*)&slab[i*72 + c16*8];
    *(f16x8*)(Ao + ((size_t)(b * SEQ + q0 + wave*32 + i)) * DMODEL + h * HD + c16*8) = ov;
  }
}

// ---------------- launch ----------------
// OUTPUT IS FP32. ws (>=48 MiB verified by probe):
//   xn f16 @0 (Ao alias after QKV) | Qb @8M (WoutT alias after attn)
//   Kb @16M | Vt @24M | WqkvT @32M (6MB)
extern "C" void kernel_launch(void* const* d_in, const int* in_sizes, int n_in,
                              void* d_out, int out_size, void* d_ws, size_t ws_size,
                              hipStream_t stream)
{
  (void)in_sizes; (void)n_in; (void)out_size; (void)ws_size;
  const float* x     = (const float*)d_in[0];
  const float* m     = (const float*)d_in[1];
  const float* gamma = (const float*)d_in[2];
  const float* beta  = (const float*)d_in[3];
  const float* Wqkv  = (const float*)d_in[4];
  const float* Wout  = (const float*)d_in[5];
  float* out = (float*)d_out;

  char* ws = (char*)d_ws;
  f16* xn    = (f16*)(ws + 0);
  f16* Ao    = (f16*)(ws + 0);            // alias: xn dead after gemm_qkv
  f16* Qb    = (f16*)(ws + 8388608);
  f16* WoutT = (f16*)(ws + 8388608);      // alias: Qb dead after attn
  f16* Kbuf  = (f16*)(ws + 16777216);
  f16* Vtb   = (f16*)(ws + 25165824);
  f16* WqkvT = (f16*)(ws + 33554432);

  ln_kernel<<<ROWS, 256, 0, stream>>>(x, gamma, beta, xn);
  transpose_f2h_kernel<<<dim3(NQKV/32, DMODEL/32), 256, 0, stream>>>(Wqkv, WqkvT, DMODEL, NQKV);
  gemm_qkv<<<dim3(NQKV/128, ROWS/128), 256, 0, stream>>>(xn, WqkvT, Qb, Kbuf, Vtb);
  attn_kernel<<<dim3(SEQ/128, BATCH*NH), 256, 0, stream>>>(Qb, Kbuf, Vtb, m, Ao);
  transpose_f2h_kernel<<<dim3(DMODEL/32, DMODEL/32), 256, 0, stream>>>(Wout, WoutT, DMODEL, DMODEL);
  gemm_out<<<dim3(DMODEL/128, ROWS/64), 256, 0, stream>>>(Ao, WoutT, out, ROWS, DMODEL, DMODEL);
}